// Round 3
// baseline (742.771 us; speedup 1.0000x reference)
//
#include <hip/hip_runtime.h>

// Problem constants: T=32768 tokens, H=2048 hidden, I=768 intermediate
#define T_TOK 32768
#define H_DIM 2048
#define I_DIM 768
#define N1_DIM 1536   // 2*I

typedef unsigned short ushort_t;
typedef __attribute__((ext_vector_type(8))) short  short8;   // 8 bf16 = 4 VGPRs (MFMA A/B frag)
typedef __attribute__((ext_vector_type(4))) float  floatx4;  // MFMA C/D frag

// ---- bf16 helpers (raw-bit, RNE) ----
__device__ __forceinline__ ushort_t f2bf(float f) {
    union { float f; unsigned u; } v; v.f = f;
    unsigned u = v.u;
    unsigned r = (u + 0x7fffu + ((u >> 16) & 1u)) >> 16;
    return (ushort_t)r;
}

// ---- async global->LDS, 16B per lane (dest = wave-uniform base + lane*16) ----
typedef __attribute__((address_space(1))) const void gq_t;
typedef __attribute__((address_space(3))) void lq_t;
__device__ __forceinline__ void gld_lds16(const void* g, void* l) {
    __builtin_amdgcn_global_load_lds((gq_t*)g, (lq_t*)l, 16, 0, 0);
}

// =====================================================================
// cast fp32 -> bf16, 8 elems/thread (grid*256*8 == n exactly)
// =====================================================================
__global__ __launch_bounds__(256) void cast_f32_bf16_k(
    const float* __restrict__ in, ushort_t* __restrict__ out)
{
    size_t i = ((size_t)blockIdx.x * 256 + threadIdx.x) * 8;
    const float4 a = *(const float4*)(in + i);
    const float4 b = *(const float4*)(in + i + 4);
    short8 o;
    o[0] = (short)f2bf(a.x); o[1] = (short)f2bf(a.y);
    o[2] = (short)f2bf(a.z); o[3] = (short)f2bf(a.w);
    o[4] = (short)f2bf(b.x); o[5] = (short)f2bf(b.y);
    o[6] = (short)f2bf(b.z); o[7] = (short)f2bf(b.w);
    *(short8*)(out + i) = o;
}

// =====================================================================
// gate/up pairing permutation for wgu_t rows:
//   source col c (c<768: gate c ; c>=768: up c-768) -> out row
//   pair group of 32 rows = [16 gate cols | 16 up cols] for the same ci range.
// =====================================================================
__device__ __forceinline__ int gu_perm(int c) {
    const int t  = (c >= I_DIM) ? 1 : 0;
    const int cc = c - t * I_DIM;
    return ((cc >> 4) << 5) + (t << 4) + (cc & 15);
}

// =====================================================================
// transpose + cast: in fp32 [R][C] -> out bf16 [perm(C)][R]  (R,C mult of 32)
// =====================================================================
template <bool PERM>
__global__ __launch_bounds__(256) void transpose_cast_k(
    const float* __restrict__ in, ushort_t* __restrict__ out, int R, int C)
{
    __shared__ float tile[32][33];
    const int c0 = blockIdx.x * 32;
    const int r0 = blockIdx.y * 32;
    const int tx = threadIdx.x;   // 0..31
    const int ty = threadIdx.y;   // 0..7
#pragma unroll
    for (int dy = 0; dy < 32; dy += 8)
        tile[ty + dy][tx] = in[(size_t)(r0 + ty + dy) * C + (c0 + tx)];
    __syncthreads();
#pragma unroll
    for (int dy = 0; dy < 32; dy += 8) {
        const int c = c0 + ty + dy;
        const int orow = PERM ? gu_perm(c) : c;
        out[(size_t)orow * R + (r0 + tx)] = f2bf(tile[tx][ty + dy]);
    }
}

// =====================================================================
// bf16 GEMM, C = A @ Bt^T — 256x256 tile, BK=64, 512 thr (8 waves, 2Mx4N),
// double-buffered 128 KiB LDS, 4-phase/K-tile schedule, counted vmcnt
// (T3+T4), setprio around MFMA (T5), bijective XCD swizzle + n-fastest
// block decomposition (T1).
//
// LDS layout (ushort idx): A[buf][256 rows][64 k] at 0, B at +32768.
// XOR-swizzled 8-elem k-groups (T2, measured 0 conflicts): element
// (r, kgroup g) stored at slot (g ^ (r&7)); staging pre-swizzles the
// per-lane GLOBAL k-offset, LDS dest stays linear (rule #21).
//
// Pipeline (v3 — all drained loads get >=3 phases of cover):
//   issues: P0 -> A-mh0',B-h0',B-h1' (6)   P1 -> A-mh1' (2)
//   drains: end-P0 vmcnt(6)  (waits A-mh1 of cur tile, issued 3 ph ago)
//           end-P3 vmcnt(2)  (waits A-mh0'+B',      issued 3 ph ago,
//                             keeps A-mh1' in flight)
//   never vmcnt(0) in the main loop.
//
// EPI==0: fp32 C store.  EPI==1: paired gate/up -> x = silu(g)*u, bf16.
// =====================================================================
#define GB    __builtin_amdgcn_s_barrier()
#define SB0   __builtin_amdgcn_sched_barrier(0)
#define LGKM0 asm volatile("s_waitcnt lgkmcnt(0)" ::: "memory")
#define VMW(N) asm volatile("s_waitcnt vmcnt(" #N ")" ::: "memory")

template <int EPI, int NBN>
__global__ __launch_bounds__(512, 2) void gemm_bt8(
    const ushort_t* __restrict__ A,
    const ushort_t* __restrict__ Bt,
    void* __restrict__ Cv,
    int lda, int ldb, int ldc, int K)
{
    __shared__ __align__(16) ushort_t lds[65536];   // 128 KiB

    const int tid  = threadIdx.x;
    const int lane = tid & 63;
    const int wave = tid >> 6;
    const int wm   = (wave >> 2) * 128;   // wave origin rows within tile
    const int wn   = (wave & 3) * 64;     // wave origin cols within tile
    const int s    = lane & 15;
    const int q    = lane >> 4;
    const int s7   = s & 7;

    // bijective XCD swizzle (gridDim.x % 8 == 0), then n-fastest decompose:
    // blocks sharing an A-panel sit adjacently on one XCD -> L2 A reuse.
    const int nwg = gridDim.x;
    const int cpx = nwg >> 3;
    const int wg  = blockIdx.x;
    const int swz = (wg & 7) * cpx + (wg >> 3);
    const int mb  = swz / NBN;            // compile-time NBN -> magic mul
    const int m0  = mb * 256;
    const int n0  = (swz - mb * NBN) * 256;

    // staging: lane -> (row3 = lane>>3, slot = lane&7), global kgroup = slot^row3
    const int r3 = lane >> 3;
    const int sk = ((lane & 7) ^ r3) * 8;
    const ushort_t* Ab = A  + (size_t)(m0 + wave * 8 + r3) * lda + sk;
    const ushort_t* Bb = Bt + (size_t)(n0 + wave * 8 + r3) * ldb + sk;

    // chunk ca = wave + ofs; A: ofs {0,16} = rows [0,64)u[128,192) (mh0),
    //                           ofs {8,24} = rows [64,128)u[192,256) (mh1)
#define STAGE_A(kt, ofs, b) gld_lds16(Ab + (size_t)((ofs) * 8) * lda + (kt), \
                                      &lds[(b) * 16384 + (wave + (ofs)) * 512])
#define STAGE_B(kt, ofs, b) gld_lds16(Bb + (size_t)((ofs) * 8) * ldb + (kt), \
                                      &lds[32768 + (b) * 16384 + (wave + (ofs)) * 512])

    const int arow = wm + s;
    const int brow = wn + s;
#define LDA4(b, ks, mh, av) { _Pragma("unroll") for (int ii = 0; ii < 4; ++ii) \
    av[ii] = *(const short8*)&lds[(b) * 16384 + (arow + (mh) * 64 + ii * 16) * 64 \
                                  + (((ks) * 4 + q) ^ s7) * 8]; }
#define LDB4(b, ks, bv) { _Pragma("unroll") for (int jj = 0; jj < 4; ++jj) \
    bv[jj] = *(const short8*)&lds[32768 + (b) * 16384 + (brow + jj * 16) * 64 \
                                  + (((ks) * 4 + q) ^ s7) * 8]; }
#define MFMA16(mh, av, bv) { _Pragma("unroll") for (int ii = 0; ii < 4; ++ii) \
    _Pragma("unroll") for (int jj = 0; jj < 4; ++jj) \
        acc[(mh) * 4 + ii][jj] = __builtin_amdgcn_mfma_f32_16x16x32_bf16( \
            av[ii], bv[jj], acc[(mh) * 4 + ii][jj], 0, 0, 0); }

    floatx4 acc[8][4];
#pragma unroll
    for (int i = 0; i < 8; ++i)
#pragma unroll
        for (int j = 0; j < 4; ++j)
            acc[i][j] = floatx4{0.f, 0.f, 0.f, 0.f};

    const int NT = K >> 6;

    // ---- prologue: stage tile 0 into buf 0; keep A-mh1 in flight (steady entry)
    STAGE_A(0, 0, 0);  STAGE_A(0, 16, 0);
    STAGE_B(0, 0, 0);  STAGE_B(0, 8, 0);
    STAGE_B(0, 16, 0); STAGE_B(0, 24, 0);
    STAGE_A(0, 8, 0);  STAGE_A(0, 24, 0);
    VMW(2);               // A-mh0 + B landed; A-mh1 (2 loads) still in flight
    GB; SB0;

    for (int t = 0; t < NT - 1; ++t) {
        const int b   = t & 1;
        const int nb  = b ^ 1;
        const int kt1 = (t + 1) << 6;
        short8 av[4], bv[4];
        // P0: ks=0, m-half 0 ; issue A-mh0' + B' (6 loads)
        LDA4(b, 0, 0, av); LDB4(b, 0, bv);
        STAGE_A(kt1, 0, nb);  STAGE_A(kt1, 16, nb);
        STAGE_B(kt1, 0, nb);  STAGE_B(kt1, 8, nb);
        STAGE_B(kt1, 16, nb); STAGE_B(kt1, 24, nb);
        GB; LGKM0; SB0;
        __builtin_amdgcn_s_setprio(1); MFMA16(0, av, bv); __builtin_amdgcn_s_setprio(0);
        VMW(6);           // drain A-mh1 of tile t (issued 3 phases ago); keep the 6
        GB;
        // P1: ks=0, m-half 1 (reuse bv) ; issue A-mh1' (2 loads)
        LDA4(b, 0, 1, av);
        STAGE_A(kt1, 8, nb); STAGE_A(kt1, 24, nb);
        GB; LGKM0; SB0;
        __builtin_amdgcn_s_setprio(1); MFMA16(1, av, bv); __builtin_amdgcn_s_setprio(0);
        GB;
        // P2: ks=1, m-half 0 ; no issues
        LDA4(b, 1, 0, av); LDB4(b, 1, bv);
        GB; LGKM0; SB0;
        __builtin_amdgcn_s_setprio(1); MFMA16(0, av, bv); __builtin_amdgcn_s_setprio(0);
        GB;
        // P3: ks=1, m-half 1 ; no issues
        LDA4(b, 1, 1, av);
        GB; LGKM0; SB0;
        __builtin_amdgcn_s_setprio(1); MFMA16(1, av, bv); __builtin_amdgcn_s_setprio(0);
        VMW(2);           // drain A-mh0'+B' (issued 3 phases ago); keep A-mh1'
        GB;
    }
    // ---- peeled last tile (no prefetch)
    {
        const int b = (NT - 1) & 1;
        short8 av[4], bv[4];
        LDA4(b, 0, 0, av); LDB4(b, 0, bv);
        GB; LGKM0; SB0;
        __builtin_amdgcn_s_setprio(1); MFMA16(0, av, bv); __builtin_amdgcn_s_setprio(0);
        VMW(0);           // drain A-mh1 of last tile
        GB;
        LDA4(b, 0, 1, av);
        GB; LGKM0; SB0;
        __builtin_amdgcn_s_setprio(1); MFMA16(1, av, bv); __builtin_amdgcn_s_setprio(0);
        GB;
        LDA4(b, 1, 0, av); LDB4(b, 1, bv);
        GB; LGKM0; SB0;
        __builtin_amdgcn_s_setprio(1); MFMA16(0, av, bv); __builtin_amdgcn_s_setprio(0);
        GB;
        LDA4(b, 1, 1, av);
        LGKM0; SB0;
        __builtin_amdgcn_s_setprio(1); MFMA16(1, av, bv); __builtin_amdgcn_s_setprio(0);
    }

    // epilogue: C/D layout col = lane&15, row = quad*4 + reg  (m89-verified)
    if (EPI == 0) {
        float* C = (float*)Cv;
#pragma unroll
        for (int i = 0; i < 8; ++i) {
            const int r = m0 + wm + i * 16 + q * 4;
#pragma unroll
            for (int j = 0; j < 4; ++j) {
                const int cn = n0 + wn + j * 16 + s;
#pragma unroll
                for (int tt = 0; tt < 4; ++tt)
                    C[(size_t)(r + tt) * ldc + cn] = acc[i][j][tt];
            }
        }
    } else {
        // paired layout: frag j even = gate, j odd = up, same lanes.
        // output col ci = (n0+wn)/2 + (j>>1)*16 + s
        ushort_t* X = (ushort_t*)Cv;
        const int cb2 = (n0 + wn) >> 1;
#pragma unroll
        for (int i = 0; i < 8; ++i) {
            const int r = m0 + wm + i * 16 + q * 4;
#pragma unroll
            for (int jp = 0; jp < 2; ++jp) {
                const int cn = cb2 + jp * 16 + s;
#pragma unroll
                for (int tt = 0; tt < 4; ++tt) {
                    const float g  = acc[i][2 * jp][tt];
                    const float u  = acc[i][2 * jp + 1][tt];
                    const float sv = g / (1.0f + __expf(-g));
                    X[(size_t)(r + tt) * ldc + cn] = f2bf(sv * u);
                }
            }
        }
    }
#undef STAGE_A
#undef STAGE_B
#undef LDA4
#undef LDB4
#undef MFMA16
}

// =====================================================================
extern "C" void kernel_launch(void* const* d_in, const int* in_sizes, int n_in,
                              void* d_out, int out_size, void* d_ws, size_t ws_size,
                              hipStream_t stream)
{
    const float* hs  = (const float*)d_in[0];  // [32768][2048]
    const float* wgu = (const float*)d_in[1];  // [2048][1536]
    const float* wd  = (const float*)d_in[2];  // [768][2048]
    float*       out = (float*)d_out;          // [32768][2048] fp32

    // workspace layout (bytes): wgu_t | wd_t | x
    char* ws = (char*)d_ws;
    ushort_t* wgu_t = (ushort_t*)ws;                          // [1536][2048] bf16 (gu-paired rows)
    ushort_t* wd_t  = (ushort_t*)(ws + 6291456);              // [2048][768]  bf16
    ushort_t* xb    = (ushort_t*)(ws + 9437184);              // [32768][768] bf16

    // d_out doubles as scratch for bf16 activations (GEMM2 overwrites all of out)
    ushort_t* hs_b = (ushort_t*)d_out;                        // [32768][2048] bf16, 134217728 B

    // 1. cast activations fp32->bf16
    cast_f32_bf16_k<<<32768, 256, 0, stream>>>(hs, hs_b);
    // 2. transpose-cast weights to [N][K] bf16 (wgu with gate/up row pairing)
    transpose_cast_k<true><<<dim3(N1_DIM / 32, H_DIM / 32), dim3(32, 8), 0, stream>>>(
        wgu, wgu_t, H_DIM, N1_DIM);
    transpose_cast_k<false><<<dim3(H_DIM / 32, I_DIM / 32), dim3(32, 8), 0, stream>>>(
        wd, wd_t, I_DIM, H_DIM);
    // 3. GEMM1 (+fused SiLU*mul): x = silu(gate)*up, written directly as bf16 [32768][768]
    gemm_bt8<1, 6><<<(T_TOK / 256) * (N1_DIM / 256), 512, 0, stream>>>(
        hs_b, wgu_t, (void*)xb, H_DIM, H_DIM, I_DIM, H_DIM);
    // 4. GEMM2: out = x @ Wd   [32768][2048] fp32
    gemm_bt8<0, 8><<<(T_TOK / 256) * (H_DIM / 256), 512, 0, stream>>>(
        xb, wd_t, (void*)out, I_DIM, I_DIM, H_DIM, I_DIM);
}

// Round 4
// 736.607 us; speedup vs baseline: 1.0084x; 1.0084x over previous
//
#include <hip/hip_runtime.h>

// Problem constants: T=32768 tokens, H=2048 hidden, I=768 intermediate
#define T_TOK 32768
#define H_DIM 2048
#define I_DIM 768
#define N1_DIM 1536   // 2*I

typedef unsigned short ushort_t;
typedef __attribute__((ext_vector_type(8))) short  short8;   // 8 bf16 = 4 VGPRs (MFMA A/B frag)
typedef __attribute__((ext_vector_type(4))) float  floatx4;  // MFMA C/D frag

// ---- bf16 helpers (raw-bit, RNE) ----
__device__ __forceinline__ ushort_t f2bf(float f) {
    union { float f; unsigned u; } v; v.f = f;
    unsigned u = v.u;
    unsigned r = (u + 0x7fffu + ((u >> 16) & 1u)) >> 16;
    return (ushort_t)r;
}

// ---- async global->LDS, 16B per lane (dest = wave-uniform base + lane*16) ----
typedef __attribute__((address_space(1))) const void gq_t;
typedef __attribute__((address_space(3))) void lq_t;
__device__ __forceinline__ void gld_lds16(const void* g, void* l) {
    __builtin_amdgcn_global_load_lds((gq_t*)g, (lq_t*)l, 16, 0, 0);
}

// pack 4 floats -> 4 bf16 (RNE) as 2 dwords via v_cvt_pk_bf16_f32
__device__ __forceinline__ void cvtpk4(float x0, float x1, float x2, float x3,
                                       unsigned& w0, unsigned& w1) {
    asm("v_cvt_pk_bf16_f32 %0, %1, %2" : "=v"(w0) : "v"(x0), "v"(x1));
    asm("v_cvt_pk_bf16_f32 %0, %1, %2" : "=v"(w1) : "v"(x2), "v"(x3));
}

// =====================================================================
// gate/up pairing permutation for wgu_t rows:
//   source col c (c<768: gate c ; c>=768: up c-768) -> out row
//   pair group of 32 rows = [16 gate cols | 16 up cols] for the same ci range.
// =====================================================================
__device__ __forceinline__ int gu_perm(int c) {
    const int t  = (c >= I_DIM) ? 1 : 0;
    const int cc = c - t * I_DIM;
    return ((cc >> 4) << 5) + (t << 4) + (cc & 15);
}

// =====================================================================
// transpose + cast: in fp32 [R][C] -> out bf16 [perm(C)][R]  (R,C mult of 32)
// =====================================================================
template <bool PERM>
__global__ __launch_bounds__(256) void transpose_cast_k(
    const float* __restrict__ in, ushort_t* __restrict__ out, int R, int C)
{
    __shared__ float tile[32][33];
    const int c0 = blockIdx.x * 32;
    const int r0 = blockIdx.y * 32;
    const int tx = threadIdx.x;   // 0..31
    const int ty = threadIdx.y;   // 0..7
#pragma unroll
    for (int dy = 0; dy < 32; dy += 8)
        tile[ty + dy][tx] = in[(size_t)(r0 + ty + dy) * C + (c0 + tx)];
    __syncthreads();
#pragma unroll
    for (int dy = 0; dy < 32; dy += 8) {
        const int c = c0 + ty + dy;
        const int orow = PERM ? gu_perm(c) : c;
        out[(size_t)orow * R + (r0 + tx)] = f2bf(tile[tx][ty + dy]);
    }
}

#define GB    __builtin_amdgcn_s_barrier()
#define SB0   __builtin_amdgcn_sched_barrier(0)
#define LGKM0 asm volatile("s_waitcnt lgkmcnt(0)" ::: "memory")
#define VMW(N) asm volatile("s_waitcnt vmcnt(" #N ")" ::: "memory")

// =====================================================================
// GEMM2 (R2-proven schedule): C = A @ Bt^T, bf16 A/B, fp32 C.
// 256x256 tile, BK=64, 512 thr (8 waves), dbuf 128 KiB LDS, 4-phase
// counted-vmcnt pipeline, setprio, XCD swizzle + n-fastest decompose.
// =====================================================================
template <int NBN>
__global__ __launch_bounds__(512, 2) void gemm_bt8(
    const ushort_t* __restrict__ A,
    const ushort_t* __restrict__ Bt,
    float* __restrict__ C,
    int lda, int ldb, int ldc, int K)
{
    __shared__ __align__(16) ushort_t lds[65536];   // 128 KiB

    const int tid  = threadIdx.x;
    const int lane = tid & 63;
    const int wave = tid >> 6;
    const int wm   = (wave >> 2) * 128;
    const int wn   = (wave & 3) * 64;
    const int s    = lane & 15;
    const int q    = lane >> 4;
    const int s7   = s & 7;

    const int nwg = gridDim.x;
    const int cpx = nwg >> 3;
    const int wg  = blockIdx.x;
    const int swz = (wg & 7) * cpx + (wg >> 3);
    const int mb  = swz / NBN;
    const int m0  = mb * 256;
    const int n0  = (swz - mb * NBN) * 256;

    const int r3 = lane >> 3;
    const int sk = ((lane & 7) ^ r3) * 8;
    const ushort_t* Ab = A  + (size_t)(m0 + wave * 8 + r3) * lda + sk;
    const ushort_t* Bb = Bt + (size_t)(n0 + wave * 8 + r3) * ldb + sk;

#define STAGE_A(kt, ofs, b) gld_lds16(Ab + (size_t)((ofs) * 8) * lda + (kt), \
                                      &lds[(b) * 16384 + (wave + (ofs)) * 512])
#define STAGE_B(kt, ofs, b) gld_lds16(Bb + (size_t)((ofs) * 8) * ldb + (kt), \
                                      &lds[32768 + (b) * 16384 + (wave + (ofs)) * 512])

    const int arow = wm + s;
    const int brow = wn + s;
#define LDA4(b, ks, mh, av) { _Pragma("unroll") for (int ii = 0; ii < 4; ++ii) \
    av[ii] = *(const short8*)&lds[(b) * 16384 + (arow + (mh) * 64 + ii * 16) * 64 \
                                  + (((ks) * 4 + q) ^ s7) * 8]; }
#define LDB4(b, ks, bv) { _Pragma("unroll") for (int jj = 0; jj < 4; ++jj) \
    bv[jj] = *(const short8*)&lds[32768 + (b) * 16384 + (brow + jj * 16) * 64 \
                                  + (((ks) * 4 + q) ^ s7) * 8]; }
#define MFMA16(mh, av, bv) { _Pragma("unroll") for (int ii = 0; ii < 4; ++ii) \
    _Pragma("unroll") for (int jj = 0; jj < 4; ++jj) \
        acc[(mh) * 4 + ii][jj] = __builtin_amdgcn_mfma_f32_16x16x32_bf16( \
            av[ii], bv[jj], acc[(mh) * 4 + ii][jj], 0, 0, 0); }

    floatx4 acc[8][4];
#pragma unroll
    for (int i = 0; i < 8; ++i)
#pragma unroll
        for (int j = 0; j < 4; ++j)
            acc[i][j] = floatx4{0.f, 0.f, 0.f, 0.f};

    const int NT = K >> 6;

    STAGE_A(0, 0, 0);  STAGE_A(0, 16, 0);
    STAGE_B(0, 0, 0);  STAGE_B(0, 8, 0);
    STAGE_B(0, 16, 0); STAGE_B(0, 24, 0);
    STAGE_A(0, 8, 0);  STAGE_A(0, 24, 0);
    VMW(2);
    GB; SB0;

    for (int t = 0; t < NT - 1; ++t) {
        const int b   = t & 1;
        const int nb  = b ^ 1;
        const int kt1 = (t + 1) << 6;
        short8 av[4], bv[4];
        // P0
        LDA4(b, 0, 0, av); LDB4(b, 0, bv);
        STAGE_A(kt1, 0, nb); STAGE_A(kt1, 16, nb);
        GB; LGKM0; SB0;
        __builtin_amdgcn_s_setprio(1); MFMA16(0, av, bv); __builtin_amdgcn_s_setprio(0);
        VMW(2);
        GB;
        // P1
        LDA4(b, 0, 1, av);
        STAGE_B(kt1, 0, nb); STAGE_B(kt1, 8, nb);
        GB; LGKM0; SB0;
        __builtin_amdgcn_s_setprio(1); MFMA16(1, av, bv); __builtin_amdgcn_s_setprio(0);
        GB;
        // P2
        LDA4(b, 1, 0, av); LDB4(b, 1, bv);
        STAGE_B(kt1, 16, nb); STAGE_B(kt1, 24, nb);
        GB; LGKM0; SB0;
        __builtin_amdgcn_s_setprio(1); MFMA16(0, av, bv); __builtin_amdgcn_s_setprio(0);
        GB;
        // P3
        LDA4(b, 1, 1, av);
        STAGE_A(kt1, 8, nb); STAGE_A(kt1, 24, nb);
        GB; LGKM0; SB0;
        __builtin_amdgcn_s_setprio(1); MFMA16(1, av, bv); __builtin_amdgcn_s_setprio(0);
        VMW(2);
        GB;
    }
    {
        const int b = (NT - 1) & 1;
        short8 av[4], bv[4];
        LDA4(b, 0, 0, av); LDB4(b, 0, bv);
        GB; LGKM0; SB0;
        __builtin_amdgcn_s_setprio(1); MFMA16(0, av, bv); __builtin_amdgcn_s_setprio(0);
        VMW(0);
        GB;
        LDA4(b, 0, 1, av);
        GB; LGKM0; SB0;
        __builtin_amdgcn_s_setprio(1); MFMA16(1, av, bv); __builtin_amdgcn_s_setprio(0);
        GB;
        LDA4(b, 1, 0, av); LDB4(b, 1, bv);
        GB; LGKM0; SB0;
        __builtin_amdgcn_s_setprio(1); MFMA16(0, av, bv); __builtin_amdgcn_s_setprio(0);
        GB;
        LDA4(b, 1, 1, av);
        LGKM0; SB0;
        __builtin_amdgcn_s_setprio(1); MFMA16(1, av, bv); __builtin_amdgcn_s_setprio(0);
    }

    // epilogue: fp32 store. C/D layout col = lane&15, row = quad*4 + reg
#pragma unroll
    for (int i = 0; i < 8; ++i) {
        const int r = m0 + wm + i * 16 + q * 4;
#pragma unroll
        for (int j = 0; j < 4; ++j) {
            const int cn = n0 + wn + j * 16 + s;
#pragma unroll
            for (int tt = 0; tt < 4; ++tt)
                C[(size_t)(r + tt) * ldc + cn] = acc[i][j][tt];
        }
    }
#undef STAGE_A
#undef STAGE_B
#undef LDA4
#undef LDB4
#undef MFMA16
}

// =====================================================================
// GEMM1 + fused fp32->bf16 A-cast + fused SiLU*mul epilogue.
//   A  : fp32 [32768][2048] (raw activations; cast done in-staging)
//   Bt : bf16 [1536][2048] gu-paired rows
//   X  : bf16 [32768][768] = silu(gate)*up
// Same 256x256/BK=64/4-phase R2 schedule; A staged via reg (T14 split:
// float4 loads issued 2 phases early, cvt_pk + ds_write_b128 after the
// covering MFMA).  A is lgkm-synced; vmcnt tracks {A-floats, B-gloads}:
//   issue: P0 mh0'(4 float4), P1 mh1'(4 float4) + B(2 gload), P2 B(2)
//   drain: end-P2 vmcnt(8) -> mh0' (2-ph cover), write it
//          end-P3 vmcnt(4) -> mh1' (2-ph cover), write it; vmcnt(0) -> B;
//          lgkmcnt(0) before the tile-swap barrier (writes visible).
// =====================================================================
template <int NBN>
__global__ __launch_bounds__(512, 2) void gemm1_fused(
    const float* __restrict__ A,
    const ushort_t* __restrict__ Bt,
    ushort_t* __restrict__ X)
{
    __shared__ __align__(16) ushort_t lds[65536];   // 128 KiB

    const int tid  = threadIdx.x;
    const int lane = tid & 63;
    const int wave = tid >> 6;
    const int wm   = (wave >> 2) * 128;
    const int wn   = (wave & 3) * 64;
    const int s    = lane & 15;
    const int q    = lane >> 4;
    const int s7   = s & 7;

    const int nwg = gridDim.x;
    const int cpx = nwg >> 3;
    const int wg  = blockIdx.x;
    const int swz = (wg & 7) * cpx + (wg >> 3);
    const int mb  = swz / NBN;
    const int m0  = mb * 256;
    const int n0  = (swz - mb * NBN) * 256;

    const int r3 = lane >> 3;
    const int sk = ((lane & 7) ^ r3) * 8;       // pre-swizzled k-offset (elems)
    const float*    Af = A  + (size_t)(m0 + wave * 8 + r3) * H_DIM + sk;
    const ushort_t* Bb = Bt + (size_t)(n0 + wave * 8 + r3) * H_DIM + sk;

#define LOADF(kt, ofs, fa, fb) { \
    fa = *(const float4*)(Af + (size_t)((ofs) * 8) * H_DIM + (kt)); \
    fb = *(const float4*)(Af + (size_t)((ofs) * 8) * H_DIM + (kt) + 4); }
#define WRITEF(ofs, b, fa, fb) { unsigned w0_, w1_, w2_, w3_; \
    cvtpk4(fa.x, fa.y, fa.z, fa.w, w0_, w1_); \
    cvtpk4(fb.x, fb.y, fb.z, fb.w, w2_, w3_); \
    *(uint4*)&lds[(b) * 16384 + (wave + (ofs)) * 512 + lane * 8] = \
        make_uint4(w0_, w1_, w2_, w3_); }
#define STAGE_B(kt, ofs, b) gld_lds16(Bb + (size_t)((ofs) * 8) * H_DIM + (kt), \
                                      &lds[32768 + (b) * 16384 + (wave + (ofs)) * 512])

    const int arow = wm + s;
    const int brow = wn + s;
#define LDA4(b, ks, mh, av) { _Pragma("unroll") for (int ii = 0; ii < 4; ++ii) \
    av[ii] = *(const short8*)&lds[(b) * 16384 + (arow + (mh) * 64 + ii * 16) * 64 \
                                  + (((ks) * 4 + q) ^ s7) * 8]; }
#define LDB4(b, ks, bv) { _Pragma("unroll") for (int jj = 0; jj < 4; ++jj) \
    bv[jj] = *(const short8*)&lds[32768 + (b) * 16384 + (brow + jj * 16) * 64 \
                                  + (((ks) * 4 + q) ^ s7) * 8]; }
#define MFMA16(mh, av, bv) { _Pragma("unroll") for (int ii = 0; ii < 4; ++ii) \
    _Pragma("unroll") for (int jj = 0; jj < 4; ++jj) \
        acc[(mh) * 4 + ii][jj] = __builtin_amdgcn_mfma_f32_16x16x32_bf16( \
            av[ii], bv[jj], acc[(mh) * 4 + ii][jj], 0, 0, 0); }

    floatx4 acc[8][4];
#pragma unroll
    for (int i = 0; i < 8; ++i)
#pragma unroll
        for (int j = 0; j < 4; ++j)
            acc[i][j] = floatx4{0.f, 0.f, 0.f, 0.f};

    const int NT = H_DIM >> 6;   // 32
    float4 a0, a1, a2, a3;       // A-mh0' chunks (ofs 0, 16)
    float4 c0, c1, c2, c3;       // A-mh1' chunks (ofs 8, 24)

    // ---- prologue: tile 0 into buf 0
    LOADF(0, 0, a0, a1);  LOADF(0, 16, a2, a3);     // 4 VMEM (mh0)
    LOADF(0, 8, c0, c1);  LOADF(0, 24, c2, c3);     // 4 VMEM (mh1)
    STAGE_B(0, 0, 0);  STAGE_B(0, 8, 0);
    STAGE_B(0, 16, 0); STAGE_B(0, 24, 0);           // 4 VMEM (B)
    VMW(8);  WRITEF(0, 0, a0, a1);  WRITEF(16, 0, a2, a3);
    VMW(4);  WRITEF(8, 0, c0, c1);  WRITEF(24, 0, c2, c3);
    VMW(0);
    LGKM0; GB; SB0;

    for (int t = 0; t < NT - 1; ++t) {
        const int b   = t & 1;
        const int nb  = b ^ 1;
        const int kt1 = (t + 1) << 6;
        short8 av[4], bv[4];
        // P0: frags ks0/mh0 ; issue A-mh0' floats
        LDA4(b, 0, 0, av); LDB4(b, 0, bv);
        LOADF(kt1, 0, a0, a1); LOADF(kt1, 16, a2, a3);
        GB; LGKM0; SB0;
        __builtin_amdgcn_s_setprio(1); MFMA16(0, av, bv); __builtin_amdgcn_s_setprio(0);
        GB;
        // P1: frags ks0/mh1 ; issue A-mh1' floats + B' h0
        LDA4(b, 0, 1, av);
        LOADF(kt1, 8, c0, c1); LOADF(kt1, 24, c2, c3);
        STAGE_B(kt1, 0, nb); STAGE_B(kt1, 8, nb);
        GB; LGKM0; SB0;
        __builtin_amdgcn_s_setprio(1); MFMA16(1, av, bv); __builtin_amdgcn_s_setprio(0);
        GB;
        // P2: frags ks1/mh0 ; issue B' h1 ; drain+write A-mh0'
        LDA4(b, 1, 0, av); LDB4(b, 1, bv);
        STAGE_B(kt1, 16, nb); STAGE_B(kt1, 24, nb);
        GB; LGKM0; SB0;
        __builtin_amdgcn_s_setprio(1); MFMA16(0, av, bv); __builtin_amdgcn_s_setprio(0);
        VMW(8);   // outstanding 12 {mh0'4, mh1'4, B4} -> drains mh0' (2-ph cover)
        WRITEF(0, nb, a0, a1); WRITEF(16, nb, a2, a3);
        GB;
        // P3: frags ks1/mh1 ; drain+write A-mh1' ; drain B' ; publish writes
        LDA4(b, 1, 1, av);
        GB; LGKM0; SB0;
        __builtin_amdgcn_s_setprio(1); MFMA16(1, av, bv); __builtin_amdgcn_s_setprio(0);
        VMW(4);   // drains mh1' (2-ph cover), keeps B'
        WRITEF(8, nb, c0, c1); WRITEF(24, nb, c2, c3);
        VMW(0);   // B' landed
        LGKM0;    // ds_writes visible before tile swap
        GB;
    }
    // ---- peeled last tile
    {
        const int b = (NT - 1) & 1;
        short8 av[4], bv[4];
        LDA4(b, 0, 0, av); LDB4(b, 0, bv);
        GB; LGKM0; SB0;
        __builtin_amdgcn_s_setprio(1); MFMA16(0, av, bv); __builtin_amdgcn_s_setprio(0);
        GB;
        LDA4(b, 0, 1, av);
        GB; LGKM0; SB0;
        __builtin_amdgcn_s_setprio(1); MFMA16(1, av, bv); __builtin_amdgcn_s_setprio(0);
        GB;
        LDA4(b, 1, 0, av); LDB4(b, 1, bv);
        GB; LGKM0; SB0;
        __builtin_amdgcn_s_setprio(1); MFMA16(0, av, bv); __builtin_amdgcn_s_setprio(0);
        GB;
        LDA4(b, 1, 1, av);
        LGKM0; SB0;
        __builtin_amdgcn_s_setprio(1); MFMA16(1, av, bv); __builtin_amdgcn_s_setprio(0);
    }

    // epilogue: paired gate/up -> x = silu(g)*u, bf16
    const int cb2 = (n0 + wn) >> 1;
#pragma unroll
    for (int i = 0; i < 8; ++i) {
        const int r = m0 + wm + i * 16 + q * 4;
#pragma unroll
        for (int jp = 0; jp < 2; ++jp) {
            const int cn = cb2 + jp * 16 + s;
#pragma unroll
            for (int tt = 0; tt < 4; ++tt) {
                const float g  = acc[i][2 * jp][tt];
                const float u  = acc[i][2 * jp + 1][tt];
                const float sv = g / (1.0f + __expf(-g));
                X[(size_t)(r + tt) * I_DIM + cn] = f2bf(sv * u);
            }
        }
    }
#undef LOADF
#undef WRITEF
#undef STAGE_B
#undef LDA4
#undef LDB4
#undef MFMA16
}

// =====================================================================
extern "C" void kernel_launch(void* const* d_in, const int* in_sizes, int n_in,
                              void* d_out, int out_size, void* d_ws, size_t ws_size,
                              hipStream_t stream)
{
    const float* hs  = (const float*)d_in[0];  // [32768][2048]
    const float* wgu = (const float*)d_in[1];  // [2048][1536]
    const float* wd  = (const float*)d_in[2];  // [768][2048]
    float*       out = (float*)d_out;          // [32768][2048] fp32

    // workspace layout (bytes): wgu_t | wd_t | x
    char* ws = (char*)d_ws;
    ushort_t* wgu_t = (ushort_t*)ws;                          // [1536][2048] bf16 (gu-paired rows)
    ushort_t* wd_t  = (ushort_t*)(ws + 6291456);              // [2048][768]  bf16
    ushort_t* xb    = (ushort_t*)(ws + 9437184);              // [32768][768] bf16

    // 1. transpose-cast weights to [N][K] bf16 (wgu with gate/up row pairing)
    transpose_cast_k<true><<<dim3(N1_DIM / 32, H_DIM / 32), dim3(32, 8), 0, stream>>>(
        wgu, wgu_t, H_DIM, N1_DIM);
    transpose_cast_k<false><<<dim3(H_DIM / 32, I_DIM / 32), dim3(32, 8), 0, stream>>>(
        wd, wd_t, I_DIM, H_DIM);
    // 2. GEMM1 (+fused A-cast + SiLU*mul): x = silu(gate)*up  [32768][768] bf16
    gemm1_fused<6><<<(T_TOK / 256) * (N1_DIM / 256), 512, 0, stream>>>(
        hs, wgu_t, xb);
    // 3. GEMM2: out = x @ Wd   [32768][2048] fp32
    gemm_bt8<8><<<(T_TOK / 256) * (H_DIM / 256), 512, 0, stream>>>(
        xb, wd_t, out, I_DIM, I_DIM, H_DIM, I_DIM);
}